// Round 2
// baseline (368.090 us; speedup 1.0000x reference)
//
#include <hip/hip_runtime.h>
#include <cstdint>
#include <cstddef>

// ---- problem constants (B=1, S=2048, H=1024, NH=16, HD=64, NT=1024) ----
#define S_LEN 2048
#define H_DIM 1024
#define NTOK  1024
#define NHEAD 16
#define HDIM  64

typedef __bf16 bf16;
typedef __bf16 bf16x8 __attribute__((ext_vector_type(8)));
typedef __bf16 bf16x4 __attribute__((ext_vector_type(4)));
typedef float  f32x4  __attribute__((ext_vector_type(4)));

static __device__ __forceinline__ f32x4 mfma16(bf16x8 a, bf16x8 b, f32x4 c) {
    return __builtin_amdgcn_mfma_f32_16x16x32_bf16(a, b, c, 0, 0, 0);
}

// ---------------------------------------------------------------------------
// fp32 -> bf16 elementwise convert, 6 jobs of 1M elements each in one launch.
// jobs 0,1 = x halves; jobs 2..5 = the 4 key matrices.
// ---------------------------------------------------------------------------
struct ConvArgs {
    const float* src[6];
    bf16* dst[6];
};
__global__ __launch_bounds__(256) void convert6(ConvArgs a) {
    const float* __restrict__ s = a.src[blockIdx.y];
    bf16* __restrict__ d = a.dst[blockIdx.y];
    size_t i = ((size_t)blockIdx.x * 256 + threadIdx.x) * 4;
    f32x4 v = *(const f32x4*)&s[i];
    bf16x4 o;
    o[0] = (bf16)v[0]; o[1] = (bf16)v[1]; o[2] = (bf16)v[2]; o[3] = (bf16)v[3];
    *(bf16x4*)&d[i] = o;
}

// ---------------------------------------------------------------------------
// fp32 1024x1024 -> transposed bf16 1024x1024 (4 matrices in one launch).
// ---------------------------------------------------------------------------
struct TcArgs {
    const float* src[4];
    bf16* dst[4];
};
__global__ void transpose_cvt(TcArgs a) {
    const float* __restrict__ in = a.src[blockIdx.z];
    bf16* __restrict__ out = a.dst[blockIdx.z];
    __shared__ float t[32][33];
    const int bx = blockIdx.x * 32, by = blockIdx.y * 32;
    const int x = threadIdx.x, y = threadIdx.y;
#pragma unroll
    for (int j = 0; j < 32; j += 8)
        t[y + j][x] = in[(size_t)(by + y + j) * 1024 + bx + x];
    __syncthreads();
#pragma unroll
    for (int j = 0; j < 32; j += 8)
        out[(size_t)(bx + y + j) * 1024 + by + x] = (bf16)t[x][y + j];
}

// ---------------------------------------------------------------------------
// GEMM: C[2048,1024] = epi( A[2048,1024] @ B[1024,1024]^T ), A,B bf16.
// MODE 0: plain store.  MODE 1: exact gelu then store.  OutT = bf16 or float.
// 128x64 tile, 256 threads (4 waves, each 64x32 = 4x2 subtiles of 16x16).
// ---------------------------------------------------------------------------
template <int MODE, typename OutT>
__global__ __launch_bounds__(256) void gemm_bt(const bf16* __restrict__ A,
                                               const bf16* __restrict__ B,
                                               OutT* __restrict__ C) {
    constexpr int Kd = 1024, Nd = 1024;
    __shared__ __align__(16) bf16 As[128][40];  // +8 pad: 80B rows, 16B aligned
    __shared__ __align__(16) bf16 Bs[64][40];

    const int tid = threadIdx.x;
    const int w = tid >> 6, lane = tid & 63, quad = lane >> 4, m16 = lane & 15;
    const int wm = (w >> 1) * 64, wn = (w & 1) * 32;
    const int bm = blockIdx.y * 128, bn = blockIdx.x * 64;

    f32x4 acc[4][2] = {};

    for (int k0 = 0; k0 < Kd; k0 += 32) {
        __syncthreads();
#pragma unroll
        for (int l = 0; l < 2; ++l) {
            int id = tid + l * 256;
            int row = id >> 2, c8 = (id & 3) * 8;
            *(bf16x8*)&As[row][c8] =
                *(const bf16x8*)&A[(size_t)(bm + row) * Kd + k0 + c8];
        }
        {
            int row = tid >> 2, c8 = (tid & 3) * 8;
            *(bf16x8*)&Bs[row][c8] =
                *(const bf16x8*)&B[(size_t)(bn + row) * Kd + k0 + c8];
        }
        __syncthreads();
        bf16x8 a[4], b[2];
#pragma unroll
        for (int i = 0; i < 4; ++i)
            a[i] = *(const bf16x8*)&As[wm + i * 16 + m16][quad * 8];
#pragma unroll
        for (int j = 0; j < 2; ++j)
            b[j] = *(const bf16x8*)&Bs[wn + j * 16 + m16][quad * 8];
#pragma unroll
        for (int i = 0; i < 4; ++i)
#pragma unroll
            for (int j = 0; j < 2; ++j)
                acc[i][j] = mfma16(a[i], b[j], acc[i][j]);
    }

#pragma unroll
    for (int i = 0; i < 4; ++i)
#pragma unroll
        for (int j = 0; j < 2; ++j)
#pragma unroll
            for (int r = 0; r < 4; ++r) {
                int row = bm + wm + i * 16 + quad * 4 + r;  // C/D: row=quad*4+reg
                int col = bn + wn + j * 16 + m16;           //      col=lane&15
                float v = acc[i][j][r];
                if (MODE == 1)
                    v = 0.5f * v * (1.0f + erff(v * 0.70710678118654752f));
                C[(size_t)row * Nd + col] = (OutT)v;
            }
}

// ---------------------------------------------------------------------------
// Row L2-normalize in place: w = g * sqrt(1024) / ||g||.  One block per row.
// ---------------------------------------------------------------------------
__global__ __launch_bounds__(256) void rownorm_kernel(bf16* __restrict__ G) {
    __shared__ float wsum[4];
    const int s = blockIdx.x, tid = threadIdx.x;
    bf16* row = G + (size_t)s * 1024;
    bf16x4 g = *(const bf16x4*)&row[tid * 4];
    float f0 = (float)g[0], f1 = (float)g[1], f2 = (float)g[2], f3 = (float)g[3];
    float ss = f0 * f0 + f1 * f1 + f2 * f2 + f3 * f3;
#pragma unroll
    for (int sh = 1; sh < 64; sh <<= 1) ss += __shfl_xor(ss, sh);
    if ((tid & 63) == 0) wsum[tid >> 6] = ss;
    __syncthreads();
    float total = wsum[0] + wsum[1] + wsum[2] + wsum[3];
    float scale = 32.0f * rsqrtf(total);  // sqrt(1024)=32
    bf16x4 o;
    o[0] = (bf16)(f0 * scale); o[1] = (bf16)(f1 * scale);
    o[2] = (bf16)(f2 * scale); o[3] = (bf16)(f3 * scale);
    *(bf16x4*)&row[tid * 4] = o;
}

// ---------------------------------------------------------------------------
// Causal flash attention. Q,K,V,O: [2048, 16*64] bf16. scale = 1/8.
// Block = (q-tile of 64, head). 4 waves; wave w owns 16 q-rows.
// QK^T and PV via 16x16x32 MFMA; V staged transposed in LDS; P via LDS.
// ---------------------------------------------------------------------------
__global__ __launch_bounds__(256) void flash_kernel(const bf16* __restrict__ Q,
                                                    const bf16* __restrict__ K,
                                                    const bf16* __restrict__ V,
                                                    bf16* __restrict__ O) {
    const int h = blockIdx.y;
    const int qt = blockIdx.x;
    const int tid = threadIdx.x;
    const int w = tid >> 6, lane = tid & 63, quad = lane >> 4, m16 = lane & 15;
    const int hOff = h * HDIM;

    __shared__ __align__(16) bf16 Vt[64][72];      // V^T tile: [d][k], pad->72
    __shared__ __align__(16) bf16 Pw[4][16][72];   // per-wave P: [qrow][kcol]

    // Q A-fragments straight from global: A[m=lane&15][k=quad*8+j]
    const int qRow = qt * 64 + w * 16 + m16;
    bf16x8 aq[2];
    aq[0] = *(const bf16x8*)&Q[(size_t)qRow * H_DIM + hOff + 0 * 32 + quad * 8];
    aq[1] = *(const bf16x8*)&Q[(size_t)qRow * H_DIM + hOff + 1 * 32 + quad * 8];

    f32x4 oacc[4] = {};           // O accumulator, C-layout, 4 d-subtiles
    float m_i[4], l_i[4];
#pragma unroll
    for (int r = 0; r < 4; ++r) { m_i[r] = -1e30f; l_i[r] = 0.0f; }

    for (int kt = 0; kt <= qt; ++kt) {
        const int k0 = kt * 64;
        __syncthreads();  // previous iter's Vt/Pw reads done
        // stage V transposed: Vt[d][kk] = V[k0+kk][hOff+d]
#pragma unroll
        for (int p = 0; p < 2; ++p) {
            int kk = (tid >> 3) + p * 32;
            int d8 = (tid & 7) * 8;
            bf16x8 v = *(const bf16x8*)&V[(size_t)(k0 + kk) * H_DIM + hOff + d8];
#pragma unroll
            for (int e = 0; e < 8; ++e) Vt[d8 + e][kk] = v[e];
        }
        // S = Q K^T  (K B-frags direct from global: B[n=lane&15][k contiguous])
        f32x4 sacc[4] = {};
#pragma unroll
        for (int ks = 0; ks < 2; ++ks)
#pragma unroll
            for (int j = 0; j < 4; ++j) {
                bf16x8 bk = *(const bf16x8*)&K[(size_t)(k0 + j * 16 + m16) * H_DIM +
                                               hOff + ks * 32 + quad * 8];
                sacc[j] = mfma16(aq[ks], bk, sacc[j]);
            }
        // online softmax per q-row (reg r); row's 64 scores live in one quad
        float alpha[4];
#pragma unroll
        for (int r = 0; r < 4; ++r) {
            const int row = qt * 64 + w * 16 + quad * 4 + r;
            float sv[4], mx = -1e30f;
#pragma unroll
            for (int j = 0; j < 4; ++j) {
                float s = sacc[j][r] * 0.125f;
                int col = k0 + j * 16 + m16;
                if (col > row) s = -1e30f;  // causal mask
                sv[j] = s;
                mx = fmaxf(mx, s);
            }
#pragma unroll
            for (int sh = 1; sh < 16; sh <<= 1) mx = fmaxf(mx, __shfl_xor(mx, sh));
            float mnew = fmaxf(m_i[r], mx);
            alpha[r] = __expf(m_i[r] - mnew);
            m_i[r] = mnew;
            float ls = 0.0f;
#pragma unroll
            for (int j = 0; j < 4; ++j) {
                float p = __expf(sv[j] - mnew);
                ls += p;
                Pw[w][quad * 4 + r][j * 16 + m16] = (bf16)p;
            }
#pragma unroll
            for (int sh = 1; sh < 16; sh <<= 1) ls += __shfl_xor(ls, sh);
            l_i[r] = l_i[r] * alpha[r] + ls;
#pragma unroll
            for (int jd = 0; jd < 4; ++jd) oacc[jd][r] *= alpha[r];
        }
        __syncthreads();  // Vt staged + P visible
        // O += P V   (P as A-frag from LDS; V^T as B-frag from LDS)
#pragma unroll
        for (int ks = 0; ks < 2; ++ks) {
            bf16x8 ap = *(const bf16x8*)&Pw[w][m16][ks * 32 + quad * 8];
#pragma unroll
            for (int jd = 0; jd < 4; ++jd) {
                bf16x8 bv = *(const bf16x8*)&Vt[jd * 16 + m16][ks * 32 + quad * 8];
                oacc[jd] = mfma16(ap, bv, oacc[jd]);
            }
        }
    }
    // epilogue: O = oacc / l
#pragma unroll
    for (int r = 0; r < 4; ++r) {
        const int row = qt * 64 + w * 16 + quad * 4 + r;
        float inv = 1.0f / l_i[r];
#pragma unroll
        for (int jd = 0; jd < 4; ++jd)
            O[(size_t)row * H_DIM + hOff + jd * 16 + m16] =
                (bf16)(oacc[jd][r] * inv);
    }
}

// ---------------------------------------------------------------------------
// Orchestration.  Inputs are FLOAT32 per the reference; output FLOAT32.
// ws layout (bytes, bf16 buffers):
//   [0,4M)    xb      bf16[2048*1024]   x converted
//   [4M,12M)  kb16[4] bf16[1024*1024]   key matrices converted
//   [12M,20M) vT16[4] bf16[1024*1024]   val matrices converted+transposed
//   [20M,24M) g       bf16[2048*1024]
//   [24M,28M) qb | [28M,32M) kbuf | [32M,36M) vbuf | [36M,40M) ctx
// ---------------------------------------------------------------------------
extern "C" void kernel_launch(void* const* d_in, const int* in_sizes, int n_in,
                              void* d_out, int out_size, void* d_ws,
                              size_t ws_size, hipStream_t stream) {
    const float* x = (const float*)d_in[0];
    const float* keysF[4] = {(const float*)d_in[1], (const float*)d_in[3],
                             (const float*)d_in[5], (const float*)d_in[7]};
    const float* valsF[4] = {(const float*)d_in[2], (const float*)d_in[4],
                             (const float*)d_in[6], (const float*)d_in[8]};
    float* out = (float*)d_out;

    char* ws = (char*)d_ws;
    bf16* xb   = (bf16*)(ws);
    bf16* kb16[4], *vT16[4];
    for (int i = 0; i < 4; ++i) {
        kb16[i] = (bf16*)(ws + (4ull << 20) + (size_t)i * (2ull << 20));
        vT16[i] = (bf16*)(ws + (12ull << 20) + (size_t)i * (2ull << 20));
    }
    bf16* g    = (bf16*)(ws + (20ull << 20));
    bf16* qb   = (bf16*)(ws + (24ull << 20));
    bf16* kbuf = (bf16*)(ws + (28ull << 20));
    bf16* vbuf = (bf16*)(ws + (32ull << 20));
    bf16* ctx  = (bf16*)(ws + (36ull << 20));

    // convert x (2 segments of 1M) + 4 key matrices (1M each)
    ConvArgs ca;
    ca.src[0] = x;             ca.dst[0] = xb;
    ca.src[1] = x + (1 << 20); ca.dst[1] = xb + (1 << 20);
    for (int i = 0; i < 4; ++i) { ca.src[2 + i] = keysF[i]; ca.dst[2 + i] = kb16[i]; }
    convert6<<<dim3(1024, 6), 256, 0, stream>>>(ca);

    // convert + transpose the 4 val matrices
    TcArgs ta;
    for (int i = 0; i < 4; ++i) { ta.src[i] = valsF[i]; ta.dst[i] = vT16[i]; }
    transpose_cvt<<<dim3(32, 32, 4), dim3(32, 8), 0, stream>>>(ta);

    auto patt = [&](const bf16* X, int pi, auto* outBuf) {
        // g = gelu(X @ key^T)
        gemm_bt<1, bf16><<<dim3(16, 16), 256, 0, stream>>>(X, kb16[pi], g);
        // w = g * 32 / ||g||   (in place)
        rownorm_kernel<<<2048, 256, 0, stream>>>(g);
        // out = w @ (val^T)^T  (== w @ val)
        gemm_bt<0><<<dim3(16, 16), 256, 0, stream>>>(g, vT16[pi], outBuf);
    };

    patt(xb, 0, qb);
    patt(xb, 1, kbuf);
    patt(xb, 2, vbuf);
    flash_kernel<<<dim3(32, 16), 256, 0, stream>>>(qb, kbuf, vbuf, ctx);
    patt(ctx, 3, out);
}

// Round 3
// 246.695 us; speedup vs baseline: 1.4921x; 1.4921x over previous
//
#include <hip/hip_runtime.h>
#include <cstdint>
#include <cstddef>

// ---- problem constants (B=1, S=2048, H=1024, NH=16, HD=64, NT=1024) ----
#define S_LEN 2048
#define H_DIM 1024
#define NTOK  1024
#define NHEAD 16
#define HDIM  64

typedef __bf16 bf16;
typedef __bf16 bf16x8 __attribute__((ext_vector_type(8)));
typedef __bf16 bf16x4 __attribute__((ext_vector_type(4)));
typedef float  f32x4  __attribute__((ext_vector_type(4)));

static __device__ __forceinline__ f32x4 mfma16(bf16x8 a, bf16x8 b, f32x4 c) {
    return __builtin_amdgcn_mfma_f32_16x16x32_bf16(a, b, c, 0, 0, 0);
}

static __device__ __forceinline__ void async16(const void* gp, void* lp) {
    __builtin_amdgcn_global_load_lds(
        (const __attribute__((address_space(1))) void*)gp,
        (__attribute__((address_space(3))) void*)lp, 16, 0, 0);
}

// ---------------------------------------------------------------------------
// fp32 -> bf16 elementwise convert, 6 jobs of 1M elements each in one launch.
// ---------------------------------------------------------------------------
struct ConvArgs {
    const float* src[6];
    bf16* dst[6];
};
__global__ __launch_bounds__(256) void convert6(ConvArgs a) {
    const float* __restrict__ s = a.src[blockIdx.y];
    bf16* __restrict__ d = a.dst[blockIdx.y];
    size_t i = ((size_t)blockIdx.x * 256 + threadIdx.x) * 4;
    f32x4 v = *(const f32x4*)&s[i];
    bf16x4 o;
    o[0] = (bf16)v[0]; o[1] = (bf16)v[1]; o[2] = (bf16)v[2]; o[3] = (bf16)v[3];
    *(bf16x4*)&d[i] = o;
}

// ---------------------------------------------------------------------------
// fp32 1024x1024 -> transposed bf16 1024x1024 (4 matrices in one launch).
// ---------------------------------------------------------------------------
struct TcArgs {
    const float* src[4];
    bf16* dst[4];
};
__global__ void transpose_cvt(TcArgs a) {
    const float* __restrict__ in = a.src[blockIdx.z];
    bf16* __restrict__ out = a.dst[blockIdx.z];
    __shared__ float t[32][33];
    const int bx = blockIdx.x * 32, by = blockIdx.y * 32;
    const int x = threadIdx.x, y = threadIdx.y;
#pragma unroll
    for (int j = 0; j < 32; j += 8)
        t[y + j][x] = in[(size_t)(by + y + j) * 1024 + bx + x];
    __syncthreads();
#pragma unroll
    for (int j = 0; j < 32; j += 8)
        out[(size_t)(bx + y + j) * 1024 + by + x] = (bf16)t[x][y + j];
}

// ---------------------------------------------------------------------------
// GEMM: C[2048,1024] = epi( A @ B^T ), A,B bf16, K=N=1024.
// 128x64 tile, BK=64, double-buffered LDS staged via global_load_lds (16B),
// global-side XOR segment swizzle for conflict-free ds_read_b128 fragments.
// 256 threads / 4 waves, each 64x32 (4x2 subtiles of 16x16x32).
// MODE 1 = exact gelu epilogue.  blockIdx.z selects A/B/C (batched QKV).
// ---------------------------------------------------------------------------
template <int MODE, typename OutT>
struct GemmArgs {
    const bf16* A[3];
    const bf16* B[3];
    OutT* C[3];
};

template <int MODE, typename OutT>
__global__ __launch_bounds__(256, 3) void gemm_bt(GemmArgs<MODE, OutT> args) {
    constexpr int Kd = 1024, Nd = 1024, BK = 64;
    const bf16* __restrict__ A = args.A[blockIdx.z];
    const bf16* __restrict__ B = args.B[blockIdx.z];
    OutT* __restrict__ C = args.C[blockIdx.z];

    __shared__ __align__(16) bf16 As[2][128 * BK];  // 2 x 16 KB
    __shared__ __align__(16) bf16 Bs[2][64 * BK];   // 2 x 8 KB

    const int tid = threadIdx.x;
    const int w = tid >> 6, lane = tid & 63, quad = lane >> 4, m16 = lane & 15;
    const int wm = (w >> 1) * 64, wn = (w & 1) * 32;
    const int bm = blockIdx.y * 128, bn = blockIdx.x * 64;

    // staging map: chunk = 8 rows x 64 cols (1 KB). lane r=lane>>3 covers a
    // row, lane&7 = 16B segment; global segment XOR-swizzled by r so that
    // LDS[row][seg] holds global seg (seg^row&7) -> conflict-free frag reads.
    const int srow = lane >> 3;
    const int sseg = ((lane & 7) ^ srow) * 8;

    auto stage = [&](int buf, int k0) {
        const bf16* Ab = A + (size_t)bm * Kd + k0;
#pragma unroll
        for (int c = 0; c < 4; ++c) {
            int chunk = w * 4 + c;
            async16(Ab + (size_t)(chunk * 8 + srow) * Kd + sseg,
                    &As[buf][chunk * 512]);
        }
        const bf16* Bb = B + (size_t)bn * Kd + k0;
#pragma unroll
        for (int c = 0; c < 2; ++c) {
            int chunk = w * 2 + c;
            async16(Bb + (size_t)(chunk * 8 + srow) * Kd + sseg,
                    &Bs[buf][chunk * 512]);
        }
    };

    f32x4 acc[4][2] = {};
    stage(0, 0);

    for (int k0 = 0; k0 < Kd; k0 += BK) {
        const int buf = (k0 >> 6) & 1;
        asm volatile("s_waitcnt vmcnt(0)" ::: "memory");
        __syncthreads();
        if (k0 + BK < Kd) stage(buf ^ 1, k0 + BK);

        bf16x8 a[2][4], b[2][2];
#pragma unroll
        for (int kc = 0; kc < 2; ++kc) {
#pragma unroll
            for (int i = 0; i < 4; ++i) {
                int row = wm + i * 16 + m16;
                a[kc][i] = *(const bf16x8*)
                    &As[buf][row * 64 + (((kc * 4 + quad) ^ (row & 7)) << 3)];
            }
#pragma unroll
            for (int j = 0; j < 2; ++j) {
                int row = wn + j * 16 + m16;
                b[kc][j] = *(const bf16x8*)
                    &Bs[buf][row * 64 + (((kc * 4 + quad) ^ (row & 7)) << 3)];
            }
        }
#pragma unroll
        for (int kc = 0; kc < 2; ++kc)
#pragma unroll
            for (int i = 0; i < 4; ++i)
#pragma unroll
                for (int j = 0; j < 2; ++j)
                    acc[i][j] = mfma16(a[kc][i], b[kc][j], acc[i][j]);
    }

#pragma unroll
    for (int i = 0; i < 4; ++i)
#pragma unroll
        for (int j = 0; j < 2; ++j)
#pragma unroll
            for (int r = 0; r < 4; ++r) {
                int row = bm + wm + i * 16 + quad * 4 + r;  // C/D: row=quad*4+reg
                int col = bn + wn + j * 16 + m16;           //      col=lane&15
                float v = acc[i][j][r];
                if (MODE == 1)
                    v = 0.5f * v * (1.0f + erff(v * 0.70710678118654752f));
                C[(size_t)row * Nd + col] = (OutT)v;
            }
}

// ---------------------------------------------------------------------------
// Row L2-normalize in place, batched over blockIdx.y.
// ---------------------------------------------------------------------------
struct NormArgs { bf16* G[3]; };
__global__ __launch_bounds__(256) void rownorm_kernel(NormArgs na) {
    __shared__ float wsum[4];
    bf16* __restrict__ G = na.G[blockIdx.y];
    const int s = blockIdx.x, tid = threadIdx.x;
    bf16* row = G + (size_t)s * 1024;
    bf16x4 g = *(const bf16x4*)&row[tid * 4];
    float f0 = (float)g[0], f1 = (float)g[1], f2 = (float)g[2], f3 = (float)g[3];
    float ss = f0 * f0 + f1 * f1 + f2 * f2 + f3 * f3;
#pragma unroll
    for (int sh = 1; sh < 64; sh <<= 1) ss += __shfl_xor(ss, sh);
    if ((tid & 63) == 0) wsum[tid >> 6] = ss;
    __syncthreads();
    float total = wsum[0] + wsum[1] + wsum[2] + wsum[3];
    float scale = 32.0f * rsqrtf(total);  // sqrt(1024)=32
    bf16x4 o;
    o[0] = (bf16)(f0 * scale); o[1] = (bf16)(f1 * scale);
    o[2] = (bf16)(f2 * scale); o[3] = (bf16)(f3 * scale);
    *(bf16x4*)&row[tid * 4] = o;
}

// ---------------------------------------------------------------------------
// Causal flash attention, 3-way K-split + paired q-tiles for load balance.
// Block = (pair, head, split); processes q-tiles {pr, 31-pr}, kt = s, s+3, ...
// Partial O (unnormalized, bf16) + (m,l) per split; combined afterwards.
// Vt staged transposed in LDS with XOR swizzle (conflict-free writes).
// ---------------------------------------------------------------------------
__global__ __launch_bounds__(256, 3) void flash_kernel(
    const bf16* __restrict__ Q, const bf16* __restrict__ K,
    const bf16* __restrict__ V, bf16* __restrict__ Opart,
    float* __restrict__ ml) {
    const int pr = blockIdx.x, h = blockIdx.y, s = blockIdx.z;
    const int tid = threadIdx.x;
    const int w = tid >> 6, lane = tid & 63, quad = lane >> 4, m16 = lane & 15;
    const int hOff = h * HDIM;

    __shared__ __align__(16) bf16 Vt[64 * 64];     // V^T tile, XOR-swizzled
    __shared__ __align__(16) bf16 Pw[4][16][72];   // per-wave P

    const int vd8 = (tid & 7) * 8;
    const int vkk = tid >> 3;

#pragma unroll
    for (int ti = 0; ti < 2; ++ti) {
        const int qt = ti ? 31 - pr : pr;
        const int qRow = qt * 64 + w * 16 + m16;
        bf16x8 aq[2];
        aq[0] = *(const bf16x8*)&Q[(size_t)qRow * H_DIM + hOff + quad * 8];
        aq[1] = *(const bf16x8*)&Q[(size_t)qRow * H_DIM + hOff + 32 + quad * 8];

        f32x4 oacc[4] = {};
        float m_i[4], l_i[4];
#pragma unroll
        for (int r = 0; r < 4; ++r) { m_i[r] = -1e30f; l_i[r] = 0.0f; }

        for (int kt = s; kt <= qt; kt += 3) {
            const int k0 = kt * 64;
            const bool diag = (kt == qt);
            __syncthreads();  // prior PV reads of Vt complete
            // stage V transposed+swizzled: Vt[d*64 + (kk ^ (d&56))] = V[kk][d]
#pragma unroll
            for (int p = 0; p < 2; ++p) {
                int kk = vkk + p * 32;
                bf16x8 v = *(const bf16x8*)&V[(size_t)(k0 + kk) * H_DIM + hOff + vd8];
#pragma unroll
                for (int e = 0; e < 8; ++e)
                    Vt[(vd8 + e) * 64 + (kk ^ vd8)] = v[e];
            }
            // S = Q K^T (K B-frags straight from global/L2)
            f32x4 sacc[4] = {};
#pragma unroll
            for (int ks = 0; ks < 2; ++ks)
#pragma unroll
                for (int j = 0; j < 4; ++j) {
                    bf16x8 bk = *(const bf16x8*)
                        &K[(size_t)(k0 + j * 16 + m16) * H_DIM + hOff + ks * 32 + quad * 8];
                    sacc[j] = mfma16(aq[ks], bk, sacc[j]);
                }
            // online softmax; only the diagonal tile needs masking
            float alpha[4];
#pragma unroll
            for (int r = 0; r < 4; ++r) {
                const int row = qt * 64 + w * 16 + quad * 4 + r;
                float sv[4], mx = -1e30f;
#pragma unroll
                for (int j = 0; j < 4; ++j) {
                    float sc = sacc[j][r] * 0.125f;
                    if (diag && (k0 + j * 16 + m16) > row) sc = -1e30f;
                    sv[j] = sc;
                    mx = fmaxf(mx, sc);
                }
#pragma unroll
                for (int sh = 1; sh < 16; sh <<= 1) mx = fmaxf(mx, __shfl_xor(mx, sh));
                float mnew = fmaxf(m_i[r], mx);
                alpha[r] = __expf(m_i[r] - mnew);
                m_i[r] = mnew;
                float ls = 0.0f;
#pragma unroll
                for (int j = 0; j < 4; ++j) {
                    float p = __expf(sv[j] - mnew);
                    ls += p;
                    Pw[w][quad * 4 + r][j * 16 + m16] = (bf16)p;
                }
#pragma unroll
                for (int sh = 1; sh < 16; sh <<= 1) ls += __shfl_xor(ls, sh);
                l_i[r] = l_i[r] * alpha[r] + ls;
#pragma unroll
                for (int jd = 0; jd < 4; ++jd) oacc[jd][r] *= alpha[r];
            }
            __syncthreads();  // Vt staged (Pw is wave-private)
            // O += P V
#pragma unroll
            for (int ks = 0; ks < 2; ++ks) {
                bf16x8 ap = *(const bf16x8*)&Pw[w][m16][ks * 32 + quad * 8];
#pragma unroll
                for (int jd = 0; jd < 4; ++jd) {
                    int d = jd * 16 + m16;
                    bf16x8 bv = *(const bf16x8*)
                        &Vt[d * 64 + ((ks * 32 + quad * 8) ^ (d & 56))];
                    oacc[jd] = mfma16(ap, bv, oacc[jd]);
                }
            }
        }
        // store split partials (unnormalized O in bf16, m/l in fp32)
#pragma unroll
        for (int r = 0; r < 4; ++r) {
            const int row = qt * 64 + w * 16 + quad * 4 + r;
#pragma unroll
            for (int jd = 0; jd < 4; ++jd)
                Opart[(size_t)(s * 2048 + row) * 1024 + hOff + jd * 16 + m16] =
                    (bf16)oacc[jd][r];
            if (m16 == 0) {
                float* p = ml + ((size_t)(s * 2048 + row) * 16 + h) * 2;
                p[0] = m_i[r];
                p[1] = l_i[r];
            }
        }
    }
}

// ---------------------------------------------------------------------------
// Combine the 3 split partials: one wave per (row, head), lane = d.
// ---------------------------------------------------------------------------
__global__ __launch_bounds__(256) void combine_kernel(
    const bf16* __restrict__ Opart, const float* __restrict__ ml,
    bf16* __restrict__ ctx) {
    const int unit = blockIdx.x * 4 + (threadIdx.x >> 6);
    const int row = unit >> 4, h = unit & 15;
    const int d = threadIdx.x & 63;
    float mv[3], lv[3], M = -1e30f;
#pragma unroll
    for (int s2 = 0; s2 < 3; ++s2) {
        const float* p = ml + ((size_t)(s2 * 2048 + row) * 16 + h) * 2;
        mv[s2] = p[0];
        lv[s2] = p[1];
        M = fmaxf(M, mv[s2]);
    }
    float num = 0.0f, den = 0.0f;
#pragma unroll
    for (int s2 = 0; s2 < 3; ++s2) {
        float e = __expf(mv[s2] - M);
        den += lv[s2] * e;
        num += e * (float)Opart[(size_t)(s2 * 2048 + row) * 1024 + h * 64 + d];
    }
    ctx[(size_t)row * 1024 + h * 64 + d] = (bf16)(num / den);
}

// ---------------------------------------------------------------------------
// Orchestration. Inputs/outputs are FLOAT32 per the reference.
// ws layout (40 MB total, phase-aliased):
//   0..4M    xb (x as bf16)            -> qb (gemm2 out) after gemm1s
//   4..16M   g3[0..2] (gelu bufs)      -> Opart[3 splits] during flash
//                                      -> proj g (4..8M) after combine
//   16..24M  kb16[0..3]  (keys bf16)
//   24..32M  vT16[0..3]  (vals^T bf16)
//   32..36M  kbuf                      -> ctx after flash
//   36..40M  vbuf
//   ml (m,l partials, 768KB fp32) lives in d_out until proj overwrites it.
// ---------------------------------------------------------------------------
extern "C" void kernel_launch(void* const* d_in, const int* in_sizes, int n_in,
                              void* d_out, int out_size, void* d_ws,
                              size_t ws_size, hipStream_t stream) {
    const float* x = (const float*)d_in[0];
    const float* keysF[4] = {(const float*)d_in[1], (const float*)d_in[3],
                             (const float*)d_in[5], (const float*)d_in[7]};
    const float* valsF[4] = {(const float*)d_in[2], (const float*)d_in[4],
                             (const float*)d_in[6], (const float*)d_in[8]};
    float* out = (float*)d_out;

    char* ws = (char*)d_ws;
    bf16* xb = (bf16*)(ws);
    bf16* g3[3];
    for (int i = 0; i < 3; ++i) g3[i] = (bf16*)(ws + (4ull << 20) + (size_t)i * (4ull << 20));
    bf16* kb16[4], *vT16[4];
    for (int i = 0; i < 4; ++i) {
        kb16[i] = (bf16*)(ws + (16ull << 20) + (size_t)i * (2ull << 20));
        vT16[i] = (bf16*)(ws + (24ull << 20) + (size_t)i * (2ull << 20));
    }
    bf16* qb    = (bf16*)(ws);                  // alias xb (dead after gemm1s)
    bf16* kbuf  = (bf16*)(ws + (32ull << 20));
    bf16* vbuf  = (bf16*)(ws + (36ull << 20));
    bf16* Opart = (bf16*)(ws + (4ull << 20));   // alias g3 (dead after gemm2s)
    bf16* ctx   = (bf16*)(ws + (32ull << 20));  // alias kbuf (dead after flash)
    bf16* projg = (bf16*)(ws + (4ull << 20));   // alias Opart (dead after combine)
    float* mlbuf = (float*)d_out;               // dead until proj gemm2

    // 1. convert x (2 x 1M) + 4 key matrices to bf16
    ConvArgs ca;
    ca.src[0] = x;             ca.dst[0] = xb;
    ca.src[1] = x + (1 << 20); ca.dst[1] = xb + (1 << 20);
    for (int i = 0; i < 4; ++i) { ca.src[2 + i] = keysF[i]; ca.dst[2 + i] = kb16[i]; }
    convert6<<<dim3(1024, 6), 256, 0, stream>>>(ca);

    // 2. convert + transpose the 4 val matrices
    TcArgs ta;
    for (int i = 0; i < 4; ++i) { ta.src[i] = valsF[i]; ta.dst[i] = vT16[i]; }
    transpose_cvt<<<dim3(32, 32, 4), dim3(32, 8), 0, stream>>>(ta);

    // 3. batched QKV pattention: g = gelu(x @ key^T)
    GemmArgs<1, bf16> g1;
    for (int z = 0; z < 3; ++z) { g1.A[z] = xb; g1.B[z] = kb16[z]; g1.C[z] = g3[z]; }
    gemm_bt<1, bf16><<<dim3(16, 16, 3), 256, 0, stream>>>(g1);

    // 4. w = g * 32 / ||g|| (in place, batched)
    NormArgs na;
    for (int z = 0; z < 3; ++z) na.G[z] = g3[z];
    rownorm_kernel<<<dim3(2048, 3), 256, 0, stream>>>(na);

    // 5. batched: {q,k,v} = w @ val
    GemmArgs<0, bf16> g2;
    bf16* qkv[3] = {qb, kbuf, vbuf};
    for (int z = 0; z < 3; ++z) { g2.A[z] = g3[z]; g2.B[z] = vT16[z]; g2.C[z] = qkv[z]; }
    gemm_bt<0, bf16><<<dim3(16, 16, 3), 256, 0, stream>>>(g2);

    // 6. flash attention (paired q-tiles, 3-way K split)
    flash_kernel<<<dim3(16, 16, 3), 256, 0, stream>>>(qb, kbuf, vbuf, Opart, mlbuf);

    // 7. combine split partials -> ctx
    combine_kernel<<<dim3(8192), 256, 0, stream>>>(Opart, mlbuf, ctx);

    // 8-10. output projection pattention
    GemmArgs<1, bf16> p1;
    p1.A[0] = ctx; p1.B[0] = kb16[3]; p1.C[0] = projg;
    for (int z = 1; z < 3; ++z) { p1.A[z] = ctx; p1.B[z] = kb16[3]; p1.C[z] = projg; }
    gemm_bt<1, bf16><<<dim3(16, 16, 1), 256, 0, stream>>>(p1);

    NormArgs np;
    for (int z = 0; z < 3; ++z) np.G[z] = projg;
    rownorm_kernel<<<dim3(2048, 1), 256, 0, stream>>>(np);

    GemmArgs<0, float> p2;
    for (int z = 0; z < 3; ++z) { p2.A[z] = projg; p2.B[z] = vT16[3]; p2.C[z] = out; }
    gemm_bt<0, float><<<dim3(16, 16, 1), 256, 0, stream>>>(p2);
}